// Round 2
// baseline (3136.430 us; speedup 1.0000x reference)
//
#include <hip/hip_runtime.h>

#define EPS_BN 1e-4f

// ---------------------------------------------------------------------------
// bn_relu: out = relu((x - m) * (g * rsqrt(v+eps)) + b)
// bn layout: [4][C] rows = gamma, beta, mean, var
// n_dev (if non-null) overrides n_const (device-resident n1).
// ---------------------------------------------------------------------------
template <int C>
__global__ __launch_bounds__(256) void bn_relu_kernel(
    const float* __restrict__ x, const float* __restrict__ bn,
    float* __restrict__ out, int n_const, const int* __restrict__ n_dev)
{
    const int n = n_dev ? *n_dev : n_const;
    const long total = (long)n * C;
    const long i = (long)blockIdx.x * blockDim.x + threadIdx.x;
    if (i >= total) return;
    const int c = (int)(i & (C - 1));
    const float g = bn[c], b = bn[C + c], m = bn[2 * C + c], v = bn[3 * C + c];
    const float val = (x[i] - m) * (g * rsqrtf(v + EPS_BN)) + b;
    out[i] = fmaxf(val, 0.f);
}

// ---------------------------------------------------------------------------
// sparse conv: out[pout[k,p]] += x[pin[k,p]] @ W[k]   (skip pin == pad)
// W layout: [K][CIN][COUT]. One thread = one (pair, cout). W[k] in LDS.
// ---------------------------------------------------------------------------
template <int CIN, int COUT>
__global__ __launch_bounds__(256) void sparse_conv_kernel(
    const float* __restrict__ x, const float* __restrict__ W,
    const int* __restrict__ pin, const int* __restrict__ pout,
    int P, int pad_const, const int* __restrict__ pad_dev,
    float* __restrict__ out)
{
    __shared__ float Wl[CIN * COUT];
    const int k = blockIdx.y;
    for (int i = threadIdx.x; i < CIN * COUT; i += 256)
        Wl[i] = W[(size_t)k * CIN * COUT + i];
    __syncthreads();

    constexpr int PPB = 256 / COUT;  // pairs per block
    const int pg = threadIdx.x / COUT;
    const int c  = threadIdx.x % COUT;
    const int p  = blockIdx.x * PPB + pg;
    if (p >= P) return;

    const int pad = pad_dev ? *pad_dev : pad_const;
    const int in  = pin[(size_t)k * P + p];
    if (in == pad) return;  // padded entry: zero contribution in reference
    const int po  = pout[(size_t)k * P + p];

    const float* xr = x + (size_t)in * CIN;
    float acc = 0.f;
#pragma unroll
    for (int q = 0; q < CIN / 4; ++q) {
        const float4 xv = *(const float4*)(xr + 4 * q);
        acc = fmaf(xv.x, Wl[(4 * q + 0) * COUT + c], acc);
        acc = fmaf(xv.y, Wl[(4 * q + 1) * COUT + c], acc);
        acc = fmaf(xv.z, Wl[(4 * q + 2) * COUT + c], acc);
        acc = fmaf(xv.w, Wl[(4 * q + 3) * COUT + c], acc);
    }
    atomicAdd(&out[(size_t)po * COUT + c], acc);
}

// ---------------------------------------------------------------------------
// concat: out[i][0:32] = a[i], out[i][32:64] = b[i]
// ---------------------------------------------------------------------------
__global__ __launch_bounds__(256) void concat_kernel(
    const float* __restrict__ a, const float* __restrict__ b,
    float* __restrict__ out, int n)
{
    const int i = blockIdx.x * 256 + threadIdx.x;
    if (i >= n * 64) return;
    const int row = i >> 6, c = i & 63;
    out[i] = (c < 32) ? a[row * 32 + c] : b[row * 32 + (c - 32)];
}

// ---------------------------------------------------------------------------
// dense matmul: out[n x 32] = x[n x 64] @ W[64 x 32]
// ---------------------------------------------------------------------------
__global__ __launch_bounds__(256) void dense_mm_kernel(
    const float* __restrict__ x, const float* __restrict__ W,
    float* __restrict__ out, int n)
{
    __shared__ float Wl[64 * 32];
    for (int i = threadIdx.x; i < 64 * 32; i += 256) Wl[i] = W[i];
    __syncthreads();
    const int idx = blockIdx.x * 256 + threadIdx.x;
    const int row = idx >> 5, c = idx & 31;
    if (row >= n) return;
    const float* xr = x + (size_t)row * 64;
    float acc = 0.f;
#pragma unroll
    for (int q = 0; q < 16; ++q) {
        const float4 xv = *(const float4*)(xr + 4 * q);
        acc = fmaf(xv.x, Wl[(4 * q + 0) * 32 + c], acc);
        acc = fmaf(xv.y, Wl[(4 * q + 1) * 32 + c], acc);
        acc = fmaf(xv.z, Wl[(4 * q + 2) * 32 + c], acc);
        acc = fmaf(xv.w, Wl[(4 * q + 3) * 32 + c], acc);
    }
    out[(size_t)row * 32 + c] = acc;
}

// ---------------------------------------------------------------------------

template <int CIN, int COUT>
static void launch_conv(const float* x, const float* W, const int* pin,
                        const int* pout, int K, int P, int pad_const,
                        const int* pad_dev, float* out, hipStream_t stream)
{
    constexpr int PPB = 256 / COUT;
    dim3 grid((P + PPB - 1) / PPB, K);
    hipLaunchKernelGGL((sparse_conv_kernel<CIN, COUT>), grid, dim3(256), 0,
                       stream, x, W, pin, pout, P, pad_const, pad_dev, out);
}

extern "C" void kernel_launch(void* const* d_in, const int* in_sizes, int n_in,
                              void* d_out, int out_size, void* d_ws, size_t ws_size,
                              hipStream_t stream)
{
    const float* feats   = (const float*)d_in[0];
    const float* res0_W  = (const float*)d_in[1];   // (2,2,27,32,32)
    const float* res0_bn = (const float*)d_in[2];   // (2,2,4,32)
    const float* down_bn = (const float*)d_in[3];   // (4,32)
    const float* down_W  = (const float*)d_in[4];   // (8,32,64)
    const float* res1_W  = (const float*)d_in[5];   // (2,2,27,64,64)
    const float* res1_bn = (const float*)d_in[6];   // (2,2,4,64)
    const float* up_bn   = (const float*)d_in[7];   // (4,64)
    const float* up_W    = (const float*)d_in[8];   // (8,64,32)
    const float* t0_bn1  = (const float*)d_in[9];   // (4,64)
    const float* t0_W1   = (const float*)d_in[10];  // (27,64,32)
    const float* t0_bn2  = (const float*)d_in[11];  // (4,32)
    const float* t0_W2   = (const float*)d_in[12];  // (27,32,32)
    const float* t0_Wsc  = (const float*)d_in[13];  // (64,32)
    const float* t1_W    = (const float*)d_in[14];  // (2,27,32,32)
    const float* t1_bn   = (const float*)d_in[15];  // (2,4,32)
    const int* s0i = (const int*)d_in[16];
    const int* s0o = (const int*)d_in[17];
    const int* s1i = (const int*)d_in[18];
    const int* s1o = (const int*)d_in[19];
    const int* dni = (const int*)d_in[20];
    const int* dno = (const int*)d_in[21];
    const int* n1p = (const int*)d_in[22];          // device scalar n1

    const int n0 = in_sizes[0] / 32;
    const int P0 = in_sizes[16] / 27;
    const int P1 = in_sizes[18] / 27;
    const int Pd = in_sizes[20] / 8;

    // scratch: five n0 x 64 fp32 buffers (level-1 rows bounded by n0 >= n1)
    const size_t bufN = (size_t)n0 * 64;
    float* B0 = (float*)d_ws;
    float* B1 = B0 + bufN;
    float* B2 = B1 + bufN;
    float* B3 = B2 + bufN;
    float* B4 = B3 + bufN;

    const int g32 = (n0 * 32 + 255) / 256;   // grid bound for C=32 elementwise
    const int g64 = (n0 * 64 + 255) / 256;

    auto bnrelu32 = [&](const float* x, const float* bn, float* out, const int* ndev) {
        hipLaunchKernelGGL((bn_relu_kernel<32>), dim3(g32), dim3(256), 0, stream,
                           x, bn, out, n0, ndev);
    };
    auto bnrelu64 = [&](const float* x, const float* bn, float* out, const int* ndev) {
        hipLaunchKernelGGL((bn_relu_kernel<64>), dim3(g64), dim3(256), 0, stream,
                           x, bn, out, n0, ndev);
    };
    auto zero  = [&](float* p, size_t elems) { hipMemsetAsync(p, 0, elems * 4, stream); };
    auto dcopy = [&](float* dst, const float* src, size_t elems) {
        hipMemcpyAsync(dst, src, elems * 4, hipMemcpyDeviceToDevice, stream);
    };

    // ---- res0 block 0: x=feats -> B2 ----
    bnrelu32(feats, res0_bn + 0 * 128, B0, nullptr);
    zero(B1, (size_t)n0 * 32);
    launch_conv<32, 32>(B0, res0_W + 0 * 27 * 1024, s0i, s0o, 27, P0, n0, nullptr, B1, stream);
    bnrelu32(B1, res0_bn + 1 * 128, B0, nullptr);
    dcopy(B2, feats, (size_t)n0 * 32);
    launch_conv<32, 32>(B0, res0_W + 1 * 27 * 1024, s0i, s0o, 27, P0, n0, nullptr, B2, stream);

    // ---- res0 block 1: B2 -> B3 (identity) ----
    bnrelu32(B2, res0_bn + 2 * 128, B0, nullptr);
    zero(B1, (size_t)n0 * 32);
    launch_conv<32, 32>(B0, res0_W + 2 * 27 * 1024, s0i, s0o, 27, P0, n0, nullptr, B1, stream);
    bnrelu32(B1, res0_bn + 3 * 128, B0, nullptr);
    dcopy(B3, B2, (size_t)n0 * 32);
    launch_conv<32, 32>(B0, res0_W + 3 * 27 * 1024, s0i, s0o, 27, P0, n0, nullptr, B3, stream);
    // identity = B3

    // ---- downsample: B3 -> x1 = B1 (n1 x 64) ----
    bnrelu32(B3, down_bn, B0, nullptr);
    zero(B1, bufN);
    launch_conv<32, 64>(B0, down_W, dni, dno, 8, Pd, n0, nullptr, B1, stream);

    // ---- res1 block 0: B1 -> B4 ----
    bnrelu64(B1, res1_bn + 0 * 256, B0, n1p);
    zero(B2, bufN);
    launch_conv<64, 64>(B0, res1_W + 0 * 27 * 4096, s1i, s1o, 27, P1, 0, n1p, B2, stream);
    bnrelu64(B2, res1_bn + 1 * 256, B0, n1p);
    dcopy(B4, B1, bufN);
    launch_conv<64, 64>(B0, res1_W + 1 * 27 * 4096, s1i, s1o, 27, P1, 0, n1p, B4, stream);

    // ---- res1 block 1: B4 -> B1 ----
    bnrelu64(B4, res1_bn + 2 * 256, B0, n1p);
    zero(B2, bufN);
    launch_conv<64, 64>(B0, res1_W + 2 * 27 * 4096, s1i, s1o, 27, P1, 0, n1p, B2, stream);
    bnrelu64(B2, res1_bn + 3 * 256, B0, n1p);
    dcopy(B1, B4, bufN);
    launch_conv<64, 64>(B0, res1_W + 3 * 27 * 4096, s1i, s1o, 27, P1, 0, n1p, B1, stream);

    // ---- upsample: B1 -> dec = B2 (n0 x 32); pin = down_out (level-1, pad n1) ----
    bnrelu64(B1, up_bn, B0, n1p);
    zero(B2, (size_t)n0 * 32);
    launch_conv<64, 32>(B0, up_W, dno, dni, 8, Pd, 0, n1p, B2, stream);

    // ---- concat: B4 = [B3 | B2] (n0 x 64) ----
    hipLaunchKernelGGL(concat_kernel, dim3(g64), dim3(256), 0, stream, B3, B2, B4, n0);

    // ---- tail0 ----
    bnrelu64(B4, t0_bn1, B0, nullptr);
    zero(B1, (size_t)n0 * 32);
    launch_conv<64, 32>(B0, t0_W1, s0i, s0o, 27, P0, n0, nullptr, B1, stream);
    bnrelu32(B1, t0_bn2, B0, nullptr);
    hipLaunchKernelGGL(dense_mm_kernel, dim3(g32), dim3(256), 0, stream, B4, t0_Wsc, B2, n0);
    launch_conv<32, 32>(B0, t0_W2, s0i, s0o, 27, P0, n0, nullptr, B2, stream);

    // ---- tail1 res block: B2 -> d_out ----
    float* outp = (float*)d_out;
    bnrelu32(B2, t1_bn + 0 * 128, B0, nullptr);
    zero(B1, (size_t)n0 * 32);
    launch_conv<32, 32>(B0, t1_W + 0 * 27 * 1024, s0i, s0o, 27, P0, n0, nullptr, B1, stream);
    bnrelu32(B1, t1_bn + 1 * 128, B0, nullptr);
    dcopy(outp, B2, (size_t)n0 * 32);
    launch_conv<32, 32>(B0, t1_W + 1 * 27 * 1024, s0i, s0o, 27, P0, n0, nullptr, outp, stream);
}